// Round 6
// baseline (240.197 us; speedup 1.0000x reference)
//
#include <hip/hip_runtime.h>
#include <hip/hip_bf16.h>

#define NND 300000
#define RR 1200
#define KADJ 20
#define BB 256
#define MM 50
#define DD 100
#define ROWS (BB*MM*KADJ)   // 256000
#define MKJ (MM*KADJ)       // 1000
#define N1P 208
#define K1S 8               // layer-1 packed K = 256 -> 8 ks steps (0..3 node, 4..7 rel)
#define NT1 7
#define NT2 7
#define K2S 4
#define H1S 136             // H1 row stride in shorts

typedef __attribute__((ext_vector_type(8))) short short8;
typedef __attribute__((ext_vector_type(4))) float f32x4;

__device__ inline unsigned short f2bf(float f) {
  union { float f; unsigned u; } v; v.f = f;
  return (unsigned short)((v.u + 0x7FFFu + ((v.u >> 16) & 1u)) >> 16);
}
__device__ inline unsigned pkbf2(float x, float y) {
  __hip_bfloat162 p = __float22bfloat162_rn(make_float2(x, y));
  unsigned u; __builtin_memcpy(&u, &p, 4); return u;
}
__device__ inline float fast_tanh(float x) {
  float e = __builtin_amdgcn_exp2f(x * 2.885390082f);
  float r = __builtin_amdgcn_rcpf(e + 1.f);
  return __builtin_fmaf(-2.f, r, 1.f);
}
__device__ inline float fast_sigmoid(float x) {
  float e = __builtin_amdgcn_exp2f(x * -1.442695041f);
  return __builtin_amdgcn_rcpf(1.f + e);
}

// ---------------- prep: packed weight fragments + G1 table ----------------
__global__ __launch_bounds__(256) void k_prep(
    const float* __restrict__ gemb,
    const float* __restrict__ aw1, const float* __restrict__ ab1,
    const float* __restrict__ cw1, const float* __restrict__ cb1,
    const float* __restrict__ aw2, const float* __restrict__ cw2,
    short* __restrict__ wf1, short* __restrict__ wf2, float* __restrict__ G1) {
  int t = blockIdx.x * blockDim.x + threadIdx.x;
  if (t < 57344) {  // wf1: 2h*7nt*8ks*64*8
    int j = t & 7, l = (t >> 3) & 63, f = t >> 9;
    int ks = f & 7, r2 = f >> 3;
    int nt = r2 % 7, h = r2 / 7;
    int kp = ks * 32 + ((l >> 4) * 8) + j;
    int n = nt * 16 + (l & 15);
    float v = 0.f;
    if (n < DD) {
      const float* w1 = h ? cw1 : aw1;
      if (kp < DD) v = w1[(DD + kp) * DD + n];
      else if (kp >= 128 && kp < 228) v = w1[(200 + kp - 128) * DD + n];
    }
    wf1[t] = (short)f2bf(v);
    return;
  }
  int t2 = t - 57344;
  if (t2 < 28672) {  // wf2
    int j = t2 & 7, l = (t2 >> 3) & 63, f = t2 >> 9;
    int ks = f & 3, r2 = f >> 2;
    int nt = r2 % 7, h = r2 / 7;
    int k = ks * 32 + ((l >> 4) * 8) + j;
    int n = nt * 16 + (l & 15);
    float v = 0.f;
    if (k < DD && n < DD) v = (h ? cw2 : aw2)[k * DD + n];
    wf2[t2] = (short)f2bf(v);
    return;
  }
  int t3 = t2 - 28672;
  if (t3 < BB * N1P) {  // G1
    int b = t3 / N1P, n = t3 % N1P;
    float acc = 0.f;
    if (n < 200) {
      const float* w1 = (n < DD) ? aw1 : cw1;
      const float* b1 = (n < DD) ? ab1 : cb1;
      int jj = (n < DD) ? n : n - DD;
      acc = b1[jj];
      for (int d = 0; d < DD; ++d) acc += gemb[b * DD + d] * w1[d * DD + jj];
    }
    G1[t3] = acc;
  }
}

// ---------------- heads: 128 rows/block, line-dense gather via LDS X-tile ----------------
template<bool FUSE>
__global__ __launch_bounds__(256, 4) void k_heads(
    const float* __restrict__ nemb, const float* __restrict__ remb,
    const float* __restrict__ oemb, const float* __restrict__ gemb,
    const int* __restrict__ eadj, const int* __restrict__ radj,
    const int* __restrict__ nodes,
    const short* __restrict__ wf1, const short* __restrict__ wf2,
    const float* __restrict__ G1,
    const float* __restrict__ ab2, const float* __restrict__ cb2,
    const float* __restrict__ aw3, const float* __restrict__ ab3,
    const float* __restrict__ cw3, const float* __restrict__ cb3,
    float* __restrict__ outA, float* __restrict__ outQ,
    float* __restrict__ dots, float* __restrict__ outNG) {
  // X (stride 128 shorts, phase A..fragment build) unioned with H1 (stride 136)
  __shared__ unsigned short Xu[128 * H1S];       // 34,816 B
  __shared__ float G1s[224], b2s[224], w3s[224];
  __shared__ float gs[112], os[112];
  __shared__ int nidS[128], ridS[128];

  unsigned short* X = Xu;
  unsigned short* H1 = Xu;

  int b = blockIdx.y, x = blockIdx.x, tid = threadIdx.x;
  int lane = tid & 63, w = tid >> 6, ln = lane & 15, lg = lane >> 4;

  // ---- index + table staging ----
  if (tid < 128) {
    int row = x * 128 + tid;
    int rc = row < MKJ ? row : MKJ - 1;
    int m = rc / KADJ, kk = rc - m * KADJ;
    int v = nodes[b * MM + m];
    nidS[tid] = eadj[v * KADJ + kk];
    ridS[tid] = radj[v * KADJ + kk];
  }
  for (int i = tid; i < 224; i += 256) {
    int h = i / 112, n = i - h * 112;
    G1s[i] = (n < DD) ? G1[b * N1P + h * DD + n] : 0.f;
    b2s[i] = (n < DD) ? (h ? cb2[n] : ab2[n]) : 0.f;
    w3s[i] = (n < DD) ? (h ? cw3[n] : aw3[n]) : 0.f;
  }
  if (FUSE) {
    for (int i = tid; i < 112; i += 256) {
      gs[i] = (i < DD) ? gemb[b * DD + i] : 0.f;
      os[i] = (i < DD) ? oemb[b * DD + i] : 0.f;
    }
  }
  __syncthreads();

  // ---- phase A: line-dense node gather -> X(bf16, swizzled); fused NG + dot ----
  {
    int rr = tid >> 2, sub = tid & 3;
    #pragma unroll
    for (int half = 0; half < 2; ++half) {
      int lrow = half * 64 + rr;            // 0..127
      int grow = x * 128 + lrow;
      bool vrow = grow < MKJ;
      const float* src = nemb + (size_t)nidS[lrow] * DD;
      float* ngr = outNG + ((size_t)b * MKJ + grow) * DD;
      float pp = 0.f;
      int swz = lrow & 7;
      #pragma unroll
      for (int it = 0; it < 8; ++it) {
        int c = sub + it * 4;               // float4 index 0..31
        int cf = c * 4;                     // float col 0..124
        float4 v = make_float4(0.f, 0.f, 0.f, 0.f);
        if (cf <= 96) v = *(const float4*)(src + cf);
        int g16 = (c >> 1) ^ swz;           // 16-B granule swizzle
        unsigned long long pk = (unsigned long long)pkbf2(v.x, v.y) |
                                ((unsigned long long)pkbf2(v.z, v.w) << 32);
        *(unsigned long long*)(X + lrow * 128 + g16 * 8 + (c & 1) * 4) = pk;
        if (FUSE && vrow && cf <= 96) {
          float4 t;
          t.x = v.x + gs[cf + 0]; t.y = v.y + gs[cf + 1];
          t.z = v.z + gs[cf + 2]; t.w = v.w + gs[cf + 3];
          *(float4*)(ngr + cf) = t;
          pp += os[cf + 0] * t.x + os[cf + 1] * t.y + os[cf + 2] * t.z + os[cf + 3] * t.w;
        }
      }
      if (FUSE) {
        pp += __shfl_xor(pp, 1, 64);
        pp += __shfl_xor(pp, 2, 64);
        if (sub == 0 && vrow) dots[(size_t)b * MKJ + grow] = pp;
      }
    }
  }
  __syncthreads();

  // ---- a1 fragments: node from X, rel direct from global (L2-resident) ----
  short8 a1[2][8];
  #pragma unroll
  for (int mt = 0; mt < 2; ++mt) {
    int lrow = w * 32 + mt * 16 + ln;
    int swz = lrow & 7;
    #pragma unroll
    for (int ks = 0; ks < 4; ++ks) {
      int g16 = (ks * 4 + lg) ^ swz;
      a1[mt][ks] = *(const short8*)(X + lrow * 128 + g16 * 8);
    }
    const float* rrow = remb + (size_t)ridS[lrow] * DD;
    #pragma unroll
    for (int ks = 4; ks < 8; ++ks) {
      int cb = (ks - 4) * 32 + lg * 8;
      float4 lo = make_float4(0.f,0.f,0.f,0.f), hi = lo;
      if (cb <= 96) lo = *(const float4*)(rrow + cb);
      if (cb + 4 <= 96) hi = *(const float4*)(rrow + cb + 4);
      union { short8 s; unsigned u[4]; } fr;
      fr.u[0] = pkbf2(lo.x, lo.y); fr.u[1] = pkbf2(lo.z, lo.w);
      fr.u[2] = pkbf2(hi.x, hi.y); fr.u[3] = pkbf2(hi.z, hi.w);
      a1[mt][ks] = fr.s;
    }
  }
  __syncthreads();   // all waves done reading X before H1 overwrites it

  // ---- H1 K-pad zero (cols 100..127 only; layer1 writes 0..99) ----
  for (int i = tid; i < 128 * 14; i += 256) {
    int row = i / 14, q = i - row * 14;
    *(unsigned*)(H1 + row * H1S + 100 + q * 2) = 0;
  }
  // no barrier needed: each wave writes its own H1 slab rows? pad covers all rows ->
  // must complete before layer2 reads; the __syncthreads after layer1 covers that.

  float b3v[2] = {ab3[0], cb3[0]};
  float* outs[2] = {outA, outQ};

  for (int h = 0; h < 2; ++h) {
    // layer 1: C-init = G1, 8 ks MFMA x 2 m-tiles, tanh -> H1
    const short8* WF1h = (const short8*)wf1 + (size_t)h * (NT1 * K1S * 64);
    for (int nt = 0; nt < NT1; ++nt) {
      int n = nt * 16 + ln;
      float g = G1s[h * 112 + n];
      f32x4 acc[2];
      #pragma unroll
      for (int mt = 0; mt < 2; ++mt) { acc[mt][0]=g; acc[mt][1]=g; acc[mt][2]=g; acc[mt][3]=g; }
      #pragma unroll
      for (int ks = 0; ks < K1S; ++ks) {
        short8 bf = WF1h[(nt * K1S + ks) * 64 + lane];
        #pragma unroll
        for (int mt = 0; mt < 2; ++mt)
          acc[mt] = __builtin_amdgcn_mfma_f32_16x16x32_bf16(a1[mt][ks], bf, acc[mt], 0, 0, 0);
      }
      if (n < DD) {
        #pragma unroll
        for (int mt = 0; mt < 2; ++mt)
          #pragma unroll
          for (int r = 0; r < 4; ++r)
            H1[(w * 32 + mt * 16 + lg * 4 + r) * H1S + n] = f2bf(fast_tanh(acc[mt][r]));
      }
    }
    __syncthreads();

    // layer 2 + 3
    const short8* WF2h = (const short8*)wf2 + (size_t)h * (NT2 * K2S * 64);
    float part[2][4] = {};
    for (int nt = 0; nt < NT2; ++nt) {
      f32x4 acc[2];
      #pragma unroll
      for (int mt = 0; mt < 2; ++mt) { acc[mt][0]=0.f; acc[mt][1]=0.f; acc[mt][2]=0.f; acc[mt][3]=0.f; }
      #pragma unroll
      for (int ks = 0; ks < K2S; ++ks) {
        short8 bf = WF2h[(nt * K2S + ks) * 64 + lane];
        #pragma unroll
        for (int mt = 0; mt < 2; ++mt) {
          short8 a2 = *(const short8*)(H1 + (w * 32 + mt * 16 + ln) * H1S + ks * 32 + lg * 8);
          acc[mt] = __builtin_amdgcn_mfma_f32_16x16x32_bf16(a2, bf, acc[mt], 0, 0, 0);
        }
      }
      int n = nt * 16 + ln;
      float b2v = b2s[h * 112 + n];
      float w3v = w3s[h * 112 + n];
      #pragma unroll
      for (int mt = 0; mt < 2; ++mt)
        #pragma unroll
        for (int r = 0; r < 4; ++r)
          part[mt][r] += fast_tanh(acc[mt][r] + b2v) * w3v;
    }
    #pragma unroll
    for (int mt = 0; mt < 2; ++mt)
      #pragma unroll
      for (int r = 0; r < 4; ++r) {
        float s = part[mt][r];
        s += __shfl_xor(s, 1, 64); s += __shfl_xor(s, 2, 64);
        s += __shfl_xor(s, 4, 64); s += __shfl_xor(s, 8, 64);
        if (ln == 0) {
          int row = x * 128 + w * 32 + mt * 16 + lg * 4 + r;
          if (row < MKJ) outs[h][(size_t)b * MKJ + row] = fast_sigmoid(s + b3v[h]);
        }
      }
    __syncthreads();
  }
}

// ---------------- softmax over raw dots (in place in outDR) ----------------
__global__ __launch_bounds__(256) void k_soft(float* __restrict__ dr) {
  __shared__ float red[4];
  int b = blockIdx.x, tid = threadIdx.x;
  int lane = tid & 63, w = tid >> 6;
  float* p = dr + (size_t)b * MKJ;
  float v[4], mx = -1e30f;
  #pragma unroll
  for (int i = 0; i < 4; ++i) {
    int j = tid + i * 256;
    v[i] = (j < MKJ) ? p[j] : -1e30f;
    mx = fmaxf(mx, v[i]);
  }
  #pragma unroll
  for (int off = 32; off; off >>= 1) mx = fmaxf(mx, __shfl_xor(mx, off, 64));
  if (lane == 0) red[w] = mx;
  __syncthreads();
  mx = fmaxf(fmaxf(red[0], red[1]), fmaxf(red[2], red[3]));
  float e[4], se = 0.f;
  #pragma unroll
  for (int i = 0; i < 4; ++i) {
    e[i] = __expf(v[i] - mx);
    if (tid + i * 256 < MKJ) se += e[i];
  }
  #pragma unroll
  for (int off = 32; off; off >>= 1) se += __shfl_xor(se, off, 64);
  __syncthreads();
  if (lane == 0) red[w] = se;
  __syncthreads();
  se = red[0] + red[1] + red[2] + red[3];
  float inv = 1.f / se;
  #pragma unroll
  for (int i = 0; i < 4; ++i) {
    int j = tid + i * 256;
    if (j < MKJ) p[j] = e[i] * inv;
  }
}

// ---------------- fallback rewards (non-fused path) ----------------
__global__ __launch_bounds__(1024) void k_rewards(
    const float* __restrict__ nemb, const float* __restrict__ oemb,
    const float* __restrict__ gemb,
    const int* __restrict__ eadj, const int* __restrict__ nodes,
    float* __restrict__ outDR, float* __restrict__ outNG) {
  __shared__ float dots[MKJ];
  __shared__ float red[16];
  int b = blockIdx.x;
  int tid = threadIdx.x;
  int lane = tid & 63, w = tid >> 6;
  int d1 = lane + 64;
  float o0 = oemb[b * DD + lane];
  float g0 = gemb[b * DD + lane];
  float o1 = (d1 < DD) ? oemb[b * DD + d1] : 0.f;
  float g1 = (d1 < DD) ? gemb[b * DD + d1] : 0.f;
  for (int j = w; j < MKJ; j += 16) {
    int m = j / KADJ, kk = j - m * KADJ;
    int v = nodes[b * MM + m];
    int nid = eadj[v * KADJ + kk];
    const float* nr = nemb + (size_t)nid * DD;
    float s0 = g0 + nr[lane];
    float s1 = (d1 < DD) ? (g1 + nr[d1]) : 0.f;
    float* ngr = outNG + ((long long)b * MKJ + j) * DD;
    ngr[lane] = s0;
    if (d1 < DD) ngr[d1] = s1;
    float p = o0 * s0 + o1 * s1;
    p += __shfl_xor(p, 1, 64); p += __shfl_xor(p, 2, 64); p += __shfl_xor(p, 4, 64);
    p += __shfl_xor(p, 8, 64); p += __shfl_xor(p, 16, 64); p += __shfl_xor(p, 32, 64);
    if (lane == 0) dots[j] = p;
  }
  __syncthreads();
  float mx = -1e30f;
  for (int j = tid; j < MKJ; j += 1024) mx = fmaxf(mx, dots[j]);
  for (int off = 32; off; off >>= 1) mx = fmaxf(mx, __shfl_xor(mx, off, 64));
  if (lane == 0) red[w] = mx;
  __syncthreads();
  mx = red[0];
  #pragma unroll
  for (int i = 1; i < 16; ++i) mx = fmaxf(mx, red[i]);
  float se = 0.f;
  for (int j = tid; j < MKJ; j += 1024) se += __expf(dots[j] - mx);
  for (int off = 32; off; off >>= 1) se += __shfl_xor(se, off, 64);
  __syncthreads();
  if (lane == 0) red[w] = se;
  __syncthreads();
  se = 0.f;
  #pragma unroll
  for (int i = 0; i < 16; ++i) se += red[i];
  float inv = 1.f / se;
  for (int j = tid; j < MKJ; j += 1024) outDR[b * MKJ + j] = __expf(dots[j] - mx) * inv;
}

extern "C" void kernel_launch(void* const* d_in, const int* in_sizes, int n_in,
                              void* d_out, int out_size, void* d_ws, size_t ws_size,
                              hipStream_t stream) {
  const float* nemb = (const float*)d_in[0];
  const float* remb = (const float*)d_in[1];
  const float* oemb = (const float*)d_in[2];
  const float* gemb = (const float*)d_in[3];
  const float* aw1 = (const float*)d_in[4];
  const float* ab1 = (const float*)d_in[5];
  const float* aw2 = (const float*)d_in[6];
  const float* ab2 = (const float*)d_in[7];
  const float* aw3 = (const float*)d_in[8];
  const float* ab3 = (const float*)d_in[9];
  const float* cw1 = (const float*)d_in[10];
  const float* cb1 = (const float*)d_in[11];
  const float* cw2 = (const float*)d_in[12];
  const float* cb2 = (const float*)d_in[13];
  const float* cw3 = (const float*)d_in[14];
  const float* cb3 = (const float*)d_in[15];
  const int* eadj = (const int*)d_in[16];
  const int* radj = (const int*)d_in[17];
  const int* nodes = (const int*)d_in[18];

  float* out = (float*)d_out;
  float* outA = out;
  float* outQ = out + ROWS;
  float* outDR = out + 2 * ROWS;
  float* outNG = out + 3 * ROWS;

  // scratch: wf1 114,688 B | wf2 57,344 B | G1 212,992 B = 385,024 B
  const size_t need = 385024;
  bool fuse = ws_size >= need;
  char* scratch = (char*)d_ws;
  if (!fuse) {
    scratch = (char*)(out + ((size_t)3 * ROWS + (size_t)ROWS * DD - need / 4));
  }
  short* wf1 = (short*)scratch;
  short* wf2 = (short*)(scratch + 114688);
  float* G1 = (float*)(scratch + 172032);

  k_prep<<<544, 256, 0, stream>>>(gemb, aw1, ab1, cw1, cb1, aw2, cw2, wf1, wf2, G1);
  dim3 hg(8, BB);
  if (fuse) {
    k_heads<true><<<hg, 256, 0, stream>>>(nemb, remb, oemb, gemb, eadj, radj, nodes,
                                          wf1, wf2, G1, ab2, cb2, aw3, ab3, cw3, cb3,
                                          outA, outQ, outDR, outNG);
    k_soft<<<BB, 256, 0, stream>>>(outDR);
  } else {
    k_heads<false><<<hg, 256, 0, stream>>>(nemb, remb, oemb, gemb, eadj, radj, nodes,
                                           wf1, wf2, G1, ab2, cb2, aw3, ab3, cw3, cb3,
                                           outA, outQ, outDR, outNG);
    k_rewards<<<BB, 1024, 0, stream>>>(nemb, oemb, gemb, eadj, nodes, outDR, outNG);
  }
}

// Round 7
// 185.683 us; speedup vs baseline: 1.2936x; 1.2936x over previous
//
#include <hip/hip_runtime.h>
#include <hip/hip_bf16.h>

#define NND 300000
#define RR 1200
#define KADJ 20
#define BB 256
#define MM 50
#define DD 100
#define ROWS (BB*MM*KADJ)   // 256000
#define MKJ (MM*KADJ)       // 1000
#define N1P 208
#define K1S 8               // layer-1 packed K = 256 -> 8 ks steps (0..3 node, 4..7 rel)
#define NT1 7
#define NT2 7
#define K2S 4
#define H1S 136             // H1 row stride in shorts

typedef __attribute__((ext_vector_type(8))) short short8;
typedef __attribute__((ext_vector_type(4))) float f32x4;

__device__ inline unsigned short f2bf(float f) {
  union { float f; unsigned u; } v; v.f = f;
  return (unsigned short)((v.u + 0x7FFFu + ((v.u >> 16) & 1u)) >> 16);
}
__device__ inline unsigned pkbf2(float x, float y) {
  __hip_bfloat162 p = __float22bfloat162_rn(make_float2(x, y));
  unsigned u; __builtin_memcpy(&u, &p, 4); return u;
}
__device__ inline float fast_tanh(float x) {
  float e = __builtin_amdgcn_exp2f(x * 2.885390082f);
  float r = __builtin_amdgcn_rcpf(e + 1.f);
  return __builtin_fmaf(-2.f, r, 1.f);
}
__device__ inline float fast_sigmoid(float x) {
  float e = __builtin_amdgcn_exp2f(x * -1.442695041f);
  return __builtin_amdgcn_rcpf(1.f + e);
}

// ---------------- prep: packed weight fragments + G1 table ----------------
__global__ __launch_bounds__(256) void k_prep(
    const float* __restrict__ gemb,
    const float* __restrict__ aw1, const float* __restrict__ ab1,
    const float* __restrict__ cw1, const float* __restrict__ cb1,
    const float* __restrict__ aw2, const float* __restrict__ cw2,
    short* __restrict__ wf1, short* __restrict__ wf2, float* __restrict__ G1) {
  int t = blockIdx.x * blockDim.x + threadIdx.x;
  if (t < 57344) {  // wf1: 2h*7nt*8ks*64*8
    int j = t & 7, l = (t >> 3) & 63, f = t >> 9;
    int ks = f & 7, r2 = f >> 3;
    int nt = r2 % 7, h = r2 / 7;
    int kp = ks * 32 + ((l >> 4) * 8) + j;
    int n = nt * 16 + (l & 15);
    float v = 0.f;
    if (n < DD) {
      const float* w1 = h ? cw1 : aw1;
      if (kp < DD) v = w1[(DD + kp) * DD + n];
      else if (kp >= 128 && kp < 228) v = w1[(200 + kp - 128) * DD + n];
    }
    wf1[t] = (short)f2bf(v);
    return;
  }
  int t2 = t - 57344;
  if (t2 < 28672) {  // wf2
    int j = t2 & 7, l = (t2 >> 3) & 63, f = t2 >> 9;
    int ks = f & 3, r2 = f >> 2;
    int nt = r2 % 7, h = r2 / 7;
    int k = ks * 32 + ((l >> 4) * 8) + j;
    int n = nt * 16 + (l & 15);
    float v = 0.f;
    if (k < DD && n < DD) v = (h ? cw2 : aw2)[k * DD + n];
    wf2[t2] = (short)f2bf(v);
    return;
  }
  int t3 = t2 - 28672;
  if (t3 < BB * N1P) {  // G1
    int b = t3 / N1P, n = t3 % N1P;
    float acc = 0.f;
    if (n < 200) {
      const float* w1 = (n < DD) ? aw1 : cw1;
      const float* b1 = (n < DD) ? ab1 : cb1;
      int jj = (n < DD) ? n : n - DD;
      acc = b1[jj];
      for (int d = 0; d < DD; ++d) acc += gemb[b * DD + d] * w1[d * DD + jj];
    }
    G1[t3] = acc;
  }
}

// ---------------- heads: 128 rows/block; gather->X; dense nt NG writes ----------------
template<bool FUSE>
__global__ __launch_bounds__(256, 4) void k_heads(
    const float* __restrict__ nemb, const float* __restrict__ remb,
    const float* __restrict__ oemb, const float* __restrict__ gemb,
    const int* __restrict__ eadj, const int* __restrict__ radj,
    const int* __restrict__ nodes,
    const short* __restrict__ wf1, const short* __restrict__ wf2,
    const float* __restrict__ G1,
    const float* __restrict__ ab2, const float* __restrict__ cb2,
    const float* __restrict__ aw3, const float* __restrict__ ab3,
    const float* __restrict__ cw3, const float* __restrict__ cb3,
    float* __restrict__ outA, float* __restrict__ outQ,
    float* __restrict__ dots, float* __restrict__ outNG) {
  // X (stride 128 shorts, phase A..A2/fragment build) unioned with H1 (stride 136)
  __shared__ unsigned short Xu[128 * H1S];       // 34,816 B
  __shared__ float G1s[224], b2s[224], w3s[224];
  __shared__ float gs[112], os[112];
  __shared__ int nidS[128], ridS[128];

  unsigned short* X = Xu;
  unsigned short* H1 = Xu;

  int b = blockIdx.y, x = blockIdx.x, tid = threadIdx.x;
  int lane = tid & 63, w = tid >> 6, ln = lane & 15, lg = lane >> 4;

  // ---- index + table staging ----
  if (tid < 128) {
    int row = x * 128 + tid;
    int rc = row < MKJ ? row : MKJ - 1;
    int m = rc / KADJ, kk = rc - m * KADJ;
    int v = nodes[b * MM + m];
    nidS[tid] = eadj[v * KADJ + kk];
    ridS[tid] = radj[v * KADJ + kk];
  }
  for (int i = tid; i < 224; i += 256) {
    int h = i / 112, n = i - h * 112;
    G1s[i] = (n < DD) ? G1[b * N1P + h * DD + n] : 0.f;
    b2s[i] = (n < DD) ? (h ? cb2[n] : ab2[n]) : 0.f;
    w3s[i] = (n < DD) ? (h ? cw3[n] : aw3[n]) : 0.f;
  }
  if (FUSE) {
    for (int i = tid; i < 112; i += 256) {
      gs[i] = (i < DD) ? gemb[b * DD + i] : 0.f;
      os[i] = (i < DD) ? oemb[b * DD + i] : 0.f;
    }
  }
  __syncthreads();

  // ---- phase A: line-dense node gather -> X(bf16, swizzled); dot only (no NG store) ----
  {
    int rr = tid >> 2, sub = tid & 3;
    #pragma unroll
    for (int half = 0; half < 2; ++half) {
      int lrow = half * 64 + rr;            // 0..127
      int grow = x * 128 + lrow;
      bool vrow = grow < MKJ;
      const float* src = nemb + (size_t)nidS[lrow] * DD;
      float pp = 0.f;
      int swz = lrow & 7;
      #pragma unroll
      for (int it = 0; it < 8; ++it) {
        int c = sub + it * 4;               // float4 index 0..31
        int cf = c * 4;                     // float col 0..124
        float4 v = make_float4(0.f, 0.f, 0.f, 0.f);
        if (cf <= 96) v = *(const float4*)(src + cf);
        int g16 = (c >> 1) ^ swz;           // 16-B granule swizzle
        unsigned long long pk = (unsigned long long)pkbf2(v.x, v.y) |
                                ((unsigned long long)pkbf2(v.z, v.w) << 32);
        *(unsigned long long*)(X + lrow * 128 + g16 * 8 + (c & 1) * 4) = pk;
        if (FUSE && cf <= 96) {
          pp += os[cf + 0] * (v.x + gs[cf + 0]) + os[cf + 1] * (v.y + gs[cf + 1]) +
                os[cf + 2] * (v.z + gs[cf + 2]) + os[cf + 3] * (v.w + gs[cf + 3]);
        }
      }
      if (FUSE) {
        pp += __shfl_xor(pp, 1, 64);
        pp += __shfl_xor(pp, 2, 64);
        if (sub == 0 && vrow) dots[(size_t)b * MKJ + grow] = pp;
      }
    }
  }
  __syncthreads();

  // ---- phase A2 (FUSE): dense NG from X (bf16 + g), each line written once, nt ----
  if (FUSE) {
    for (int j = tid; j < 128 * 25; j += 256) {
      int row = j / 25, sub = j - row * 25;       // sub = float4 col (row = 25 float4s)
      int grow = x * 128 + row;
      if (grow < MKJ) {
        int g16 = (sub >> 1) ^ (row & 7);
        const unsigned short* src = X + row * 128 + g16 * 8 + (sub & 1) * 4;
        int f0 = sub * 4;
        f32x4 t;
        #pragma unroll
        for (int q = 0; q < 4; ++q) {
          unsigned u = (unsigned)src[q] << 16;
          float vv; __builtin_memcpy(&vv, &u, 4);
          t[q] = vv + gs[f0 + q];
        }
        __builtin_nontemporal_store(t, (f32x4*)(outNG + ((size_t)b * MKJ + grow) * DD + f0));
      }
    }
  }

  // ---- a1 fragments: node from X, rel direct from global (L2-resident) ----
  short8 a1[2][8];
  #pragma unroll
  for (int mt = 0; mt < 2; ++mt) {
    int lrow = w * 32 + mt * 16 + ln;
    int swz = lrow & 7;
    #pragma unroll
    for (int ks = 0; ks < 4; ++ks) {
      int g16 = (ks * 4 + lg) ^ swz;
      a1[mt][ks] = *(const short8*)(X + lrow * 128 + g16 * 8);
    }
    const float* rrow = remb + (size_t)ridS[lrow] * DD;
    #pragma unroll
    for (int ks = 4; ks < 8; ++ks) {
      int cb = (ks - 4) * 32 + lg * 8;
      float4 lo = make_float4(0.f,0.f,0.f,0.f), hi = lo;
      if (cb <= 96) lo = *(const float4*)(rrow + cb);
      if (cb + 4 <= 96) hi = *(const float4*)(rrow + cb + 4);
      union { short8 s; unsigned u[4]; } fr;
      fr.u[0] = pkbf2(lo.x, lo.y); fr.u[1] = pkbf2(lo.z, lo.w);
      fr.u[2] = pkbf2(hi.x, hi.y); fr.u[3] = pkbf2(hi.z, hi.w);
      a1[mt][ks] = fr.s;
    }
  }
  __syncthreads();   // all waves done reading X before H1 overwrites it

  // ---- H1 K-pad zero (cols 100..127 only; layer1 writes 0..99) ----
  for (int i = tid; i < 128 * 14; i += 256) {
    int row = i / 14, q = i - row * 14;
    *(unsigned*)(H1 + row * H1S + 100 + q * 2) = 0;
  }

  float b3v[2] = {ab3[0], cb3[0]};
  float* outs[2] = {outA, outQ};

  for (int h = 0; h < 2; ++h) {
    // layer 1: C-init = G1, 8 ks MFMA x 2 m-tiles, tanh -> H1
    const short8* WF1h = (const short8*)wf1 + (size_t)h * (NT1 * K1S * 64);
    for (int nt = 0; nt < NT1; ++nt) {
      int n = nt * 16 + ln;
      float g = G1s[h * 112 + n];
      f32x4 acc[2];
      #pragma unroll
      for (int mt = 0; mt < 2; ++mt) { acc[mt][0]=g; acc[mt][1]=g; acc[mt][2]=g; acc[mt][3]=g; }
      #pragma unroll
      for (int ks = 0; ks < K1S; ++ks) {
        short8 bf = WF1h[(nt * K1S + ks) * 64 + lane];
        #pragma unroll
        for (int mt = 0; mt < 2; ++mt)
          acc[mt] = __builtin_amdgcn_mfma_f32_16x16x32_bf16(a1[mt][ks], bf, acc[mt], 0, 0, 0);
      }
      if (n < DD) {
        #pragma unroll
        for (int mt = 0; mt < 2; ++mt)
          #pragma unroll
          for (int r = 0; r < 4; ++r)
            H1[(w * 32 + mt * 16 + lg * 4 + r) * H1S + n] = f2bf(fast_tanh(acc[mt][r]));
      }
    }
    __syncthreads();

    // layer 2 + 3
    const short8* WF2h = (const short8*)wf2 + (size_t)h * (NT2 * K2S * 64);
    float part[2][4] = {};
    for (int nt = 0; nt < NT2; ++nt) {
      f32x4 acc[2];
      #pragma unroll
      for (int mt = 0; mt < 2; ++mt) { acc[mt][0]=0.f; acc[mt][1]=0.f; acc[mt][2]=0.f; acc[mt][3]=0.f; }
      #pragma unroll
      for (int ks = 0; ks < K2S; ++ks) {
        short8 bf = WF2h[(nt * K2S + ks) * 64 + lane];
        #pragma unroll
        for (int mt = 0; mt < 2; ++mt) {
          short8 a2 = *(const short8*)(H1 + (w * 32 + mt * 16 + ln) * H1S + ks * 32 + lg * 8);
          acc[mt] = __builtin_amdgcn_mfma_f32_16x16x32_bf16(a2, bf, acc[mt], 0, 0, 0);
        }
      }
      int n = nt * 16 + ln;
      float b2v = b2s[h * 112 + n];
      float w3v = w3s[h * 112 + n];
      #pragma unroll
      for (int mt = 0; mt < 2; ++mt)
        #pragma unroll
        for (int r = 0; r < 4; ++r)
          part[mt][r] += fast_tanh(acc[mt][r] + b2v) * w3v;
    }
    #pragma unroll
    for (int mt = 0; mt < 2; ++mt)
      #pragma unroll
      for (int r = 0; r < 4; ++r) {
        float s = part[mt][r];
        s += __shfl_xor(s, 1, 64); s += __shfl_xor(s, 2, 64);
        s += __shfl_xor(s, 4, 64); s += __shfl_xor(s, 8, 64);
        if (ln == 0) {
          int row = x * 128 + w * 32 + mt * 16 + lg * 4 + r;
          if (row < MKJ) outs[h][(size_t)b * MKJ + row] = fast_sigmoid(s + b3v[h]);
        }
      }
    __syncthreads();
  }
}

// ---------------- softmax over raw dots (in place in outDR) ----------------
__global__ __launch_bounds__(256) void k_soft(float* __restrict__ dr) {
  __shared__ float red[4];
  int b = blockIdx.x, tid = threadIdx.x;
  int lane = tid & 63, w = tid >> 6;
  float* p = dr + (size_t)b * MKJ;
  float v[4], mx = -1e30f;
  #pragma unroll
  for (int i = 0; i < 4; ++i) {
    int j = tid + i * 256;
    v[i] = (j < MKJ) ? p[j] : -1e30f;
    mx = fmaxf(mx, v[i]);
  }
  #pragma unroll
  for (int off = 32; off; off >>= 1) mx = fmaxf(mx, __shfl_xor(mx, off, 64));
  if (lane == 0) red[w] = mx;
  __syncthreads();
  mx = fmaxf(fmaxf(red[0], red[1]), fmaxf(red[2], red[3]));
  float e[4], se = 0.f;
  #pragma unroll
  for (int i = 0; i < 4; ++i) {
    e[i] = __expf(v[i] - mx);
    if (tid + i * 256 < MKJ) se += e[i];
  }
  #pragma unroll
  for (int off = 32; off; off >>= 1) se += __shfl_xor(se, off, 64);
  __syncthreads();
  if (lane == 0) red[w] = se;
  __syncthreads();
  se = red[0] + red[1] + red[2] + red[3];
  float inv = 1.f / se;
  #pragma unroll
  for (int i = 0; i < 4; ++i) {
    int j = tid + i * 256;
    if (j < MKJ) p[j] = e[i] * inv;
  }
}

// ---------------- fallback rewards (non-fused path) ----------------
__global__ __launch_bounds__(1024) void k_rewards(
    const float* __restrict__ nemb, const float* __restrict__ oemb,
    const float* __restrict__ gemb,
    const int* __restrict__ eadj, const int* __restrict__ nodes,
    float* __restrict__ outDR, float* __restrict__ outNG) {
  __shared__ float dots[MKJ];
  __shared__ float red[16];
  int b = blockIdx.x;
  int tid = threadIdx.x;
  int lane = tid & 63, w = tid >> 6;
  int d1 = lane + 64;
  float o0 = oemb[b * DD + lane];
  float g0 = gemb[b * DD + lane];
  float o1 = (d1 < DD) ? oemb[b * DD + d1] : 0.f;
  float g1 = (d1 < DD) ? gemb[b * DD + d1] : 0.f;
  for (int j = w; j < MKJ; j += 16) {
    int m = j / KADJ, kk = j - m * KADJ;
    int v = nodes[b * MM + m];
    int nid = eadj[v * KADJ + kk];
    const float* nr = nemb + (size_t)nid * DD;
    float s0 = g0 + nr[lane];
    float s1 = (d1 < DD) ? (g1 + nr[d1]) : 0.f;
    float* ngr = outNG + ((long long)b * MKJ + j) * DD;
    ngr[lane] = s0;
    if (d1 < DD) ngr[d1] = s1;
    float p = o0 * s0 + o1 * s1;
    p += __shfl_xor(p, 1, 64); p += __shfl_xor(p, 2, 64); p += __shfl_xor(p, 4, 64);
    p += __shfl_xor(p, 8, 64); p += __shfl_xor(p, 16, 64); p += __shfl_xor(p, 32, 64);
    if (lane == 0) dots[j] = p;
  }
  __syncthreads();
  float mx = -1e30f;
  for (int j = tid; j < MKJ; j += 1024) mx = fmaxf(mx, dots[j]);
  for (int off = 32; off; off >>= 1) mx = fmaxf(mx, __shfl_xor(mx, off, 64));
  if (lane == 0) red[w] = mx;
  __syncthreads();
  mx = red[0];
  #pragma unroll
  for (int i = 1; i < 16; ++i) mx = fmaxf(mx, red[i]);
  float se = 0.f;
  for (int j = tid; j < MKJ; j += 1024) se += __expf(dots[j] - mx);
  for (int off = 32; off; off >>= 1) se += __shfl_xor(se, off, 64);
  __syncthreads();
  if (lane == 0) red[w] = se;
  __syncthreads();
  se = 0.f;
  #pragma unroll
  for (int i = 0; i < 16; ++i) se += red[i];
  float inv = 1.f / se;
  for (int j = tid; j < MKJ; j += 1024) outDR[b * MKJ + j] = __expf(dots[j] - mx) * inv;
}

extern "C" void kernel_launch(void* const* d_in, const int* in_sizes, int n_in,
                              void* d_out, int out_size, void* d_ws, size_t ws_size,
                              hipStream_t stream) {
  const float* nemb = (const float*)d_in[0];
  const float* remb = (const float*)d_in[1];
  const float* oemb = (const float*)d_in[2];
  const float* gemb = (const float*)d_in[3];
  const float* aw1 = (const float*)d_in[4];
  const float* ab1 = (const float*)d_in[5];
  const float* aw2 = (const float*)d_in[6];
  const float* ab2 = (const float*)d_in[7];
  const float* aw3 = (const float*)d_in[8];
  const float* ab3 = (const float*)d_in[9];
  const float* cw1 = (const float*)d_in[10];
  const float* cb1 = (const float*)d_in[11];
  const float* cw2 = (const float*)d_in[12];
  const float* cb2 = (const float*)d_in[13];
  const float* cw3 = (const float*)d_in[14];
  const float* cb3 = (const float*)d_in[15];
  const int* eadj = (const int*)d_in[16];
  const int* radj = (const int*)d_in[17];
  const int* nodes = (const int*)d_in[18];

  float* out = (float*)d_out;
  float* outA = out;
  float* outQ = out + ROWS;
  float* outDR = out + 2 * ROWS;
  float* outNG = out + 3 * ROWS;

  // scratch: wf1 114,688 B | wf2 57,344 B | G1 212,992 B = 385,024 B
  const size_t need = 385024;
  bool fuse = ws_size >= need;
  char* scratch = (char*)d_ws;
  if (!fuse) {
    scratch = (char*)(out + ((size_t)3 * ROWS + (size_t)ROWS * DD - need / 4));
  }
  short* wf1 = (short*)scratch;
  short* wf2 = (short*)(scratch + 114688);
  float* G1 = (float*)(scratch + 172032);

  k_prep<<<544, 256, 0, stream>>>(gemb, aw1, ab1, cw1, cb1, aw2, cw2, wf1, wf2, G1);
  dim3 hg(8, BB);
  if (fuse) {
    k_heads<true><<<hg, 256, 0, stream>>>(nemb, remb, oemb, gemb, eadj, radj, nodes,
                                          wf1, wf2, G1, ab2, cb2, aw3, ab3, cw3, cb3,
                                          outA, outQ, outDR, outNG);
    k_soft<<<BB, 256, 0, stream>>>(outDR);
  } else {
    k_heads<false><<<hg, 256, 0, stream>>>(nemb, remb, oemb, gemb, eadj, radj, nodes,
                                           wf1, wf2, G1, ab2, cb2, aw3, ab3, cw3, cb3,
                                           outA, outQ, outDR, outNG);
    k_rewards<<<BB, 1024, 0, stream>>>(nemb, oemb, gemb, eadj, nodes, outDR, outNG);
  }
}